// Round 3
// baseline (65.317 us; speedup 1.0000x reference)
//
#include <hip/hip_runtime.h>

// Problem constants (fixed by the reference)
#define NUM_CH     5
#define GRID_DIM   32
#define CROP_LO    70          // c - 16 where c = 173/2 = 86
#define VOX_PER_B  (GRID_DIM*GRID_DIM*GRID_DIM)   // 32768

// Gather, register-resident atoms. wave64 == 64 atoms/batch: lane L caches
// atom L's (sx,sy,sz,kg,ch); the atom loop broadcasts via v_readlane (SGPR,
// no LDS traffic — R2's gather was LDS-throughput bound at ~5.8cyc/ds_read).
// Window test |g - floor(s)| <= 5  <=>  |(g+0.5) - s| <= 5.5 for non-integer s
// (degenerate exact-integer s errs by <= 0.023 < 0.0295 threshold), which
// reuses dx,dy,dz and folds to v_max3_f32(abs) + one compare.
__global__ __launch_bounds__(256) void gather_kernel(
    const float* __restrict__ coords,     // [B, 64, 3]
    const int*   __restrict__ channel,    // [B, 64]
    const float* __restrict__ radius,     // [B, 64]
    float* __restrict__ out)              // [B, 5, 32, 32, 32]
{
    const int b    = blockIdx.x >> 7;                        // 128 blocks/batch
    const int lin  = ((blockIdx.x & 127) << 8) | threadIdx.x; // voxel id
    const int lane = threadIdx.x & 63;

    // Lane L holds atom L of this batch (same data in every wave of the block).
    const int a0i = (b << 6) + lane;
    const float vsx = (coords[3*a0i + 0] + 20.0f) * 4.0f + 6.0f; // exact ref formula
    const float vsy = (coords[3*a0i + 1] + 20.0f) * 4.0f + 6.0f;
    const float vsz = (coords[3*a0i + 2] + 20.0f) * 4.0f + 6.0f;
    const float rr  = radius[a0i];
    const float vkg = -0.03125f / (rr * rr);                 // -0.5 * RES^2 / r^2
    const int   vch = channel[a0i];

    const int gx = (lin >> 10) + CROP_LO;
    const int gy = ((lin >> 5) & 31) + CROP_LO;
    const int gz = (lin & 31) + CROP_LO;
    const float fx = (float)gx + 0.5f;
    const float fy = (float)gy + 0.5f;
    const float fz = (float)gz + 0.5f;

    float c0 = 0.f, c1 = 0.f, c2 = 0.f, c3 = 0.f, c4 = 0.f;

    for (int a = 0; a < 64; ++a) {
        const float sx = __int_as_float(__builtin_amdgcn_readlane(__float_as_int(vsx), a));
        const float sy = __int_as_float(__builtin_amdgcn_readlane(__float_as_int(vsy), a));
        const float sz = __int_as_float(__builtin_amdgcn_readlane(__float_as_int(vsz), a));
        const float dx = fx - sx;
        const float dy = fy - sy;
        const float dz = fz - sz;
        const float m  = fmaxf(fmaxf(fabsf(dx), fabsf(dy)), fabsf(dz)); // v_max3 w/ abs
        if (m <= 5.5f) {                                   // execz-skip for most atoms
            const float kg = __int_as_float(__builtin_amdgcn_readlane(__float_as_int(vkg), a));
            const float val = __expf(kg * (dx*dx + dy*dy + dz*dz));
            const int ch = __builtin_amdgcn_readlane(vch, a); // wave-uniform -> s_cmp
            if      (ch == 0) c0 += val;
            else if (ch == 1) c1 += val;
            else if (ch == 2) c2 += val;
            else if (ch == 3) c3 += val;
            else              c4 += val;
        }
    }

    float* o = out + (size_t)b * NUM_CH * VOX_PER_B + lin;
    o[0*VOX_PER_B] = c0;
    o[1*VOX_PER_B] = c1;
    o[2*VOX_PER_B] = c2;
    o[3*VOX_PER_B] = c3;
    o[4*VOX_PER_B] = c4;
}

extern "C" void kernel_launch(void* const* d_in, const int* in_sizes, int n_in,
                              void* d_out, int out_size, void* d_ws, size_t ws_size,
                              hipStream_t stream) {
    const float* coords  = (const float*)d_in[0];
    const int*   channel = (const int*)d_in[1];
    const float* radius  = (const float*)d_in[2];
    float* out = (float*)d_out;

    const int B = in_sizes[1] / 64;                          // 8
    hipLaunchKernelGGL(gather_kernel, dim3(B * 128), dim3(256), 0, stream,
                       coords, channel, radius, out);
}

// Round 4
// 59.398 us; speedup vs baseline: 1.0997x; 1.0997x over previous
//
#include <hip/hip_runtime.h>

// Problem constants (fixed by the reference)
#define NUM_CH     5
#define GRID_DIM   32
#define VOX_PER_B  (GRID_DIM*GRID_DIM*GRID_DIM)   // 32768

// Gather, register-resident atoms + ballot-pruned atom loop.
// Each 256-thread block covers a 1x8x32 voxel slab (gx block-uniform).
// Lane L holds atom L of the batch (64 atoms == wave64). Prune predicate
// (exact in x, conservative in y/z) -> __ballot -> uniform 64-bit mask,
// identical across the block's 4 waves; iterate set bits with __ffsll and
// broadcast atom data via v_readlane. Expected ~2.5 live atoms/block.
// Window test |g - floor(s)| <= 5  <=>  |(g+0.5) - s| <= 5.5 for non-integer
// s (degenerate integer s errs <= 0.023 < 0.0295 threshold).
__global__ __launch_bounds__(256) void gather_kernel(
    const float* __restrict__ coords,     // [B, 64, 3]
    const int*   __restrict__ channel,    // [B, 64]
    const float* __restrict__ radius,     // [B, 64]
    float* __restrict__ out)              // [B, 5, 32, 32, 32]
{
    const int blk  = blockIdx.x & 127;                   // 128 blocks/batch
    const int b    = blockIdx.x >> 7;
    const int lin  = (blk << 8) | threadIdx.x;           // voxel id in [0,32768)
    const int lane = threadIdx.x & 63;

    // Crop-local scaled coords: s' = (c+20)*4 + 6 - 70, voxel centers at x+0.5.
    const int a0i = (b << 6) + lane;
    const float vsx = (coords[3*a0i + 0] + 20.0f) * 4.0f - 64.0f;
    const float vsy = (coords[3*a0i + 1] + 20.0f) * 4.0f - 64.0f;
    const float vsz = (coords[3*a0i + 2] + 20.0f) * 4.0f - 64.0f;
    const float rr  = radius[a0i];
    const float vkg = -0.03125f / (rr * rr);             // -0.5 * RES^2 / r^2
    const int   vch = channel[a0i];

    const int gx  = blk >> 2;                            // block-uniform
    const int gy0 = (blk & 3) << 3;                      // block's y base (8 rows)
    const float fx = (float)gx + 0.5f;
    const float fy = (float)(((lin >> 5) & 31)) + 0.5f;
    const float fz = (float)(lin & 31) + 0.5f;

    // Prune: exact in x (single gx), conservative in y (8 rows -> hw 3.5+5.5)
    // and z (32 cols -> hw 15.5+5.5). Same mask in every wave of the block.
    const bool cand = fabsf(vsx - fx) <= 5.5f &&
                      fabsf(vsy - ((float)gy0 + 4.0f)) <= 9.0f &&
                      fabsf(vsz - 16.0f) <= 21.0f;
    unsigned long long mask = __ballot(cand);

    float c0 = 0.f, c1 = 0.f, c2 = 0.f, c3 = 0.f, c4 = 0.f;

    while (mask) {
        const int a = __ffsll(mask) - 1;                 // uniform (SGPR)
        mask &= mask - 1;
        const float sx = __int_as_float(__builtin_amdgcn_readlane(__float_as_int(vsx), a));
        const float sy = __int_as_float(__builtin_amdgcn_readlane(__float_as_int(vsy), a));
        const float sz = __int_as_float(__builtin_amdgcn_readlane(__float_as_int(vsz), a));
        const float dx = fx - sx;
        const float dy = fy - sy;
        const float dz = fz - sz;
        // x-test already exact via the prune; test y,z per voxel.
        if (fmaxf(fabsf(dy), fabsf(dz)) <= 5.5f) {
            const float kg = __int_as_float(__builtin_amdgcn_readlane(__float_as_int(vkg), a));
            const float val = __expf(kg * (dx*dx + dy*dy + dz*dz));
            const int ch = __builtin_amdgcn_readlane(vch, a);  // uniform -> s_cmp
            if      (ch == 0) c0 += val;
            else if (ch == 1) c1 += val;
            else if (ch == 2) c2 += val;
            else if (ch == 3) c3 += val;
            else              c4 += val;
        }
    }

    float* o = out + (size_t)b * NUM_CH * VOX_PER_B + lin;
    o[0*VOX_PER_B] = c0;
    o[1*VOX_PER_B] = c1;
    o[2*VOX_PER_B] = c2;
    o[3*VOX_PER_B] = c3;
    o[4*VOX_PER_B] = c4;
}

extern "C" void kernel_launch(void* const* d_in, const int* in_sizes, int n_in,
                              void* d_out, int out_size, void* d_ws, size_t ws_size,
                              hipStream_t stream) {
    const float* coords  = (const float*)d_in[0];
    const int*   channel = (const int*)d_in[1];
    const float* radius  = (const float*)d_in[2];
    float* out = (float*)d_out;

    const int B = in_sizes[1] / 64;                      // 8
    hipLaunchKernelGGL(gather_kernel, dim3(B * 128), dim3(256), 0, stream,
                       coords, channel, radius, out);
}